// Round 1
// baseline (23086.711 us; speedup 1.0000x reference)
//
#include <hip/hip_runtime.h>
#include <math.h>

#define B_   32
#define L_   1024
#define C_   32
#define D_   512
#define SEG_ 16
#define SX_  64
#define N_   1024   // B*C
#define TD   32     // d-tile
#define TN   64     // n-tile
#define TK   32     // k-tile

// ---------------------------------------------------------------------------
// prep: x (B,L,C) -> xs_seg, xt_seg in (step, n, seg) layout, n = b*C + c
// moving mean is over the CHANNEL axis (reference applies _moving_mean to the
// (B,C,L) tensor over axis 1), window 25, edge replication, always /25.
// ---------------------------------------------------------------------------
__global__ __launch_bounds__(256) void prep_kernel(const float* __restrict__ x,
                                                   float* __restrict__ xs_seg,
                                                   float* __restrict__ xt_seg) {
    int b = blockIdx.x >> 2;                       // 4 chunks of 256 t per b
    int t = ((blockIdx.x & 3) << 8) + threadIdx.x; // 0..1023
    const float* xb    = x + (size_t)b * (L_ * C_);
    const float* xrow  = xb + (size_t)t * C_;
    const float* xlast = xb + (size_t)(L_ - 1) * C_;

    float diff[C_];
#pragma unroll
    for (int c = 0; c < C_; ++c) diff[c] = xrow[c] - xlast[c];

    float ps[C_ + 1];
    ps[0] = 0.f;
#pragma unroll
    for (int c = 0; c < C_; ++c) ps[c + 1] = ps[c] + diff[c];

    int s = t >> 4, q = t & 15;
#pragma unroll
    for (int c = 0; c < C_; ++c) {
        int lo = c - 12, hi = c + 12;
        float sum = ps[(hi < 31 ? hi : 31) + 1] - ps[lo > 0 ? lo : 0];
        if (lo < 0)  sum += (float)(-lo)     * diff[0];
        if (hi > 31) sum += (float)(hi - 31) * diff[31];
        float mean = sum * (1.0f / 25.0f);
        size_t idx = ((size_t)s * N_ + (size_t)(b * C_ + c)) * SEG_ + q;
        xt_seg[idx] = mean;           // trend
        xs_seg[idx] = diff[c] - mean; // seasonal
    }
}

// ---------------------------------------------------------------------------
// One GRU step for BOTH GRUs (blockIdx.z selects). mode 0: input is
// relu(seg @ W_emb^T + b_emb) (recomputed per k-tile in LDS); mode 1: input
// is the decoder pos/channel embedding.
// Block: 64 n-rows x 32 d-cols; thread: 8 rows x 1 col, 6 gate accumulators.
// ---------------------------------------------------------------------------
__global__ __launch_bounds__(256) void gru_step_kernel(
    const float* __restrict__ xseg_s, const float* __restrict__ xseg_t,
    const float* __restrict__ W_emb, const float* __restrict__ b_emb,
    const float* __restrict__ Wih_s, const float* __restrict__ Whh_s,
    const float* __restrict__ bih_s, const float* __restrict__ bhh_s,
    const float* __restrict__ Wih_t, const float* __restrict__ Whh_t,
    const float* __restrict__ bih_t, const float* __restrict__ bhh_t,
    const float* __restrict__ pos_s, const float* __restrict__ ch_s,
    const float* __restrict__ pos_t, const float* __restrict__ ch_t,
    const float* __restrict__ h_in_s, float* __restrict__ h_out_s,
    const float* __restrict__ h_in_t, float* __restrict__ h_out_t,
    int step, int mode) {

    int gru = blockIdx.z;
    int n0 = blockIdx.y * TN;
    int d0 = blockIdx.x * TD;

    const float* Wih  = gru ? Wih_t : Wih_s;
    const float* Whh  = gru ? Whh_t : Whh_s;
    const float* bih  = gru ? bih_t : bih_s;
    const float* bhh  = gru ? bhh_t : bhh_s;
    const float* xseg = gru ? xseg_t : xseg_s;
    const float* posv = gru ? pos_t : pos_s;
    const float* chv  = gru ? ch_t  : ch_s;
    const float* h_in = gru ? h_in_t : h_in_s;
    float* h_out      = gru ? h_out_t : h_out_s;

    __shared__ float xs_l[TN][SEG_];
    __shared__ float emb_l[TN][TK + 1];
    __shared__ float h_l[TN][TK + 1];
    __shared__ float wih_l[96][TK + 1];  // rows 0..31=r, 32..63=z, 64..95=n
    __shared__ float whh_l[96][TK + 1];

    int tid = threadIdx.x;

    if (mode == 0) {
        const float* src = xseg + ((size_t)step * N_ + n0) * SEG_;
        for (int i = tid; i < TN * SEG_; i += 256)
            xs_l[i >> 4][i & 15] = src[i];
    }

    int jl = tid & 31;          // local d column
    int r0 = (tid >> 5) * 8;    // first of 8 local rows

    float ai_r[8], ai_z[8], ai_n[8], ah_r[8], ah_z[8], ah_n[8];
#pragma unroll
    for (int i = 0; i < 8; ++i) {
        ai_r[i] = 0.f; ai_z[i] = 0.f; ai_n[i] = 0.f;
        ah_r[i] = 0.f; ah_z[i] = 0.f; ah_n[i] = 0.f;
    }

    for (int kt = 0; kt < D_ / TK; ++kt) {
        __syncthreads();
        int kbase = kt * TK;

        // h tile (coalesced 32-float rows)
        for (int idx = tid; idx < TN * TK; idx += 256) {
            int row = idx >> 5, kk = idx & 31;
            h_l[row][kk] = h_in[(size_t)(n0 + row) * D_ + kbase + kk];
        }
        // weight tiles
        for (int idx = tid; idx < 96 * TK; idx += 256) {
            int jr = idx >> 5, kk = idx & 31;
            int grow = (jr >> 5) * D_ + d0 + (jr & 31);
            wih_l[jr][kk] = Wih[(size_t)grow * D_ + kbase + kk];
            whh_l[jr][kk] = Whh[(size_t)grow * D_ + kbase + kk];
        }
        // input-embedding tile
        if (mode == 0) {
            for (int idx = tid; idx < TN * TK; idx += 256) {
                int row = idx >> 5, kk = idx & 31;
                int k = kbase + kk;
                float v = b_emb[k];
                const float* wrow = W_emb + (size_t)k * SEG_;
#pragma unroll
                for (int q = 0; q < SEG_; ++q) v = fmaf(xs_l[row][q], wrow[q], v);
                emb_l[row][kk] = v > 0.f ? v : 0.f;
            }
        } else {
            for (int idx = tid; idx < TN * TK; idx += 256) {
                int row = idx >> 5, kk = idx & 31;
                int k = kbase + kk;
                float v = (k < 256) ? posv[k]
                                    : chv[(size_t)((n0 + row) & 31) * 256 + (k - 256)];
                emb_l[row][kk] = v;
            }
        }
        __syncthreads();

#pragma unroll
        for (int kk = 0; kk < TK; ++kk) {
            float wir = wih_l[jl][kk];
            float wiz = wih_l[32 + jl][kk];
            float win = wih_l[64 + jl][kk];
            float whr = whh_l[jl][kk];
            float whz = whh_l[32 + jl][kk];
            float whn = whh_l[64 + jl][kk];
#pragma unroll
            for (int i = 0; i < 8; ++i) {
                float e  = emb_l[r0 + i][kk];
                float hh = h_l[r0 + i][kk];
                ai_r[i] = fmaf(e,  wir, ai_r[i]);
                ai_z[i] = fmaf(e,  wiz, ai_z[i]);
                ai_n[i] = fmaf(e,  win, ai_n[i]);
                ah_r[i] = fmaf(hh, whr, ah_r[i]);
                ah_z[i] = fmaf(hh, whz, ah_z[i]);
                ah_n[i] = fmaf(hh, whn, ah_n[i]);
            }
        }
    }

    int j = d0 + jl;
    float bir = bih[j], biz = bih[D_ + j], bin = bih[2 * D_ + j];
    float bhr = bhh[j], bhz = bhh[D_ + j], bhn = bhh[2 * D_ + j];
#pragma unroll
    for (int i = 0; i < 8; ++i) {
        int nrow = n0 + r0 + i;
        float r  = 1.f / (1.f + __expf(-(ai_r[i] + bir + ah_r[i] + bhr)));
        float z  = 1.f / (1.f + __expf(-(ai_z[i] + biz + ah_z[i] + bhz)));
        float nn = tanhf(ai_n[i] + bin + r * (ah_n[i] + bhn));
        float hp = h_in[(size_t)nrow * D_ + j];
        h_out[(size_t)nrow * D_ + j] = (1.f - z) * nn + z * hp;
    }
}

// ---------------------------------------------------------------------------
// head: y[n,p] = hs2[n,:]@Wps[p,:] + bps[p] + ht2[n,:]@Wpt[p,:] + bpt[p];
// out[b,p,c] = y[b*C+c, p] + x[b, L-1, c]
// ---------------------------------------------------------------------------
__global__ __launch_bounds__(256) void head_kernel(
    const float* __restrict__ hs2, const float* __restrict__ ht2,
    const float* __restrict__ Wps, const float* __restrict__ bps,
    const float* __restrict__ Wpt, const float* __restrict__ bpt,
    const float* __restrict__ x, float* __restrict__ out) {
    int g = blockIdx.x * 256 + threadIdx.x;  // 16384 = N_*16
    int n = g >> 4, p = g & 15;
    int b = n >> 5, c = n & 31;
    const float* hs = hs2 + (size_t)n * D_;
    const float* ht = ht2 + (size_t)n * D_;
    const float* ws = Wps + (size_t)p * D_;
    const float* wt = Wpt + (size_t)p * D_;
    float acc = bps[p] + bpt[p];
    for (int k = 0; k < D_; ++k) acc += hs[k] * ws[k] + ht[k] * wt[k];
    float last = x[((size_t)b * L_ + (L_ - 1)) * C_ + c];
    out[((size_t)b * SEG_ + p) * C_ + c] = acc + last;
}

// ---------------------------------------------------------------------------
extern "C" void kernel_launch(void* const* d_in, const int* in_sizes, int n_in,
                              void* d_out, int out_size, void* d_ws, size_t ws_size,
                              hipStream_t stream) {
    const float* x     = (const float*)d_in[0];
    const float* W_emb = (const float*)d_in[1];
    const float* b_emb = (const float*)d_in[2];
    const float* Wih_s = (const float*)d_in[3];
    const float* Whh_s = (const float*)d_in[4];
    const float* bih_s = (const float*)d_in[5];
    const float* bhh_s = (const float*)d_in[6];
    const float* Wih_t = (const float*)d_in[7];
    const float* Whh_t = (const float*)d_in[8];
    const float* bih_t = (const float*)d_in[9];
    const float* bhh_t = (const float*)d_in[10];
    const float* pos_s = (const float*)d_in[11];
    const float* ch_s  = (const float*)d_in[12];
    const float* pos_t = (const float*)d_in[13];
    const float* ch_t  = (const float*)d_in[14];
    const float* Wps   = (const float*)d_in[15];
    const float* bps   = (const float*)d_in[16];
    const float* Wpt   = (const float*)d_in[17];
    const float* bpt   = (const float*)d_in[18];
    float* out = (float*)d_out;

    float* ws_f   = (float*)d_ws;
    float* xs_seg = ws_f;                                  // 1M floats
    float* xt_seg = xs_seg + (size_t)SX_ * N_ * SEG_;      // 1M floats
    float* h_s0   = xt_seg + (size_t)SX_ * N_ * SEG_;      // 512K each
    float* h_s1   = h_s0 + (size_t)N_ * D_;
    float* h_t0   = h_s1 + (size_t)N_ * D_;
    float* h_t1   = h_t0 + (size_t)N_ * D_;

    // zero initial hidden states (ws is poisoned 0xAA before every call)
    hipMemsetAsync(h_s0, 0, sizeof(float) * N_ * D_, stream);
    hipMemsetAsync(h_t0, 0, sizeof(float) * N_ * D_, stream);

    prep_kernel<<<B_ * 4, 256, 0, stream>>>(x, xs_seg, xt_seg);

    dim3 grid(D_ / TD, N_ / TN, 2);  // (16, 16, 2)
    for (int s = 0; s < SX_; ++s) {
        const float* his = (s & 1) ? h_s1 : h_s0;
        float*       hos = (s & 1) ? h_s0 : h_s1;
        const float* hit = (s & 1) ? h_t1 : h_t0;
        float*       hot = (s & 1) ? h_t0 : h_t1;
        gru_step_kernel<<<grid, 256, 0, stream>>>(
            xs_seg, xt_seg, W_emb, b_emb,
            Wih_s, Whh_s, bih_s, bhh_s, Wih_t, Whh_t, bih_t, bhh_t,
            pos_s, ch_s, pos_t, ch_t, his, hos, hit, hot, s, 0);
    }
    // after step 63 (odd): final scan state is in h_*0. Decoder step: read *0 -> write *1.
    gru_step_kernel<<<grid, 256, 0, stream>>>(
        xs_seg, xt_seg, W_emb, b_emb,
        Wih_s, Whh_s, bih_s, bhh_s, Wih_t, Whh_t, bih_t, bhh_t,
        pos_s, ch_s, pos_t, ch_t, h_s0, h_s1, h_t0, h_t1, 0, 1);

    head_kernel<<<N_ * SEG_ / 256, 256, 0, stream>>>(
        h_s1, h_t1, Wps, bps, Wpt, bpt, x, out);
}

// Round 2
// 1668.351 us; speedup vs baseline: 13.8380x; 13.8380x over previous
//
#include <hip/hip_runtime.h>
#include <math.h>

#define B_   32
#define L_   1024
#define C_   32
#define D_   512
#define SEG_ 16
#define SX_  64
#define N_   1024   // B*C
#define GBATCH 16   // emb precompute batch (steps)

typedef _Float16 f16x8 __attribute__((ext_vector_type(8)));
typedef float    f32x4 __attribute__((ext_vector_type(4)));

__device__ __forceinline__ void stage16(const void* g, void* l) {
    __builtin_amdgcn_global_load_lds((const __attribute__((address_space(1))) void*)g,
                                     (__attribute__((address_space(3))) void*)l, 16, 0, 0);
}

// ---------------------------------------------------------------------------
// prep: x (B,L,C) -> xs_seg, xt_seg fp32 in (step, n, seg) layout, n = b*C+c.
// moving mean over the CHANNEL axis (reference semantics), window 25.
// ---------------------------------------------------------------------------
__global__ __launch_bounds__(256) void prep_kernel(const float* __restrict__ x,
                                                   float* __restrict__ xs_seg,
                                                   float* __restrict__ xt_seg) {
    int b = blockIdx.x >> 2;
    int t = ((blockIdx.x & 3) << 8) + threadIdx.x;
    const float* xb    = x + (size_t)b * (L_ * C_);
    const float* xrow  = xb + (size_t)t * C_;
    const float* xlast = xb + (size_t)(L_ - 1) * C_;

    float diff[C_];
#pragma unroll
    for (int c = 0; c < C_; ++c) diff[c] = xrow[c] - xlast[c];
    float ps[C_ + 1];
    ps[0] = 0.f;
#pragma unroll
    for (int c = 0; c < C_; ++c) ps[c + 1] = ps[c] + diff[c];

    int s = t >> 4, q = t & 15;
#pragma unroll
    for (int c = 0; c < C_; ++c) {
        int lo = c - 12, hi = c + 12;
        float sum = ps[(hi < 31 ? hi : 31) + 1] - ps[lo > 0 ? lo : 0];
        if (lo < 0)  sum += (float)(-lo)     * diff[0];
        if (hi > 31) sum += (float)(hi - 31) * diff[31];
        float mean = sum * (1.0f / 25.0f);
        size_t idx = ((size_t)s * N_ + (size_t)(b * C_ + c)) * SEG_ + q;
        xt_seg[idx] = mean;
        xs_seg[idx] = diff[c] - mean;
    }
}

// ---------------------------------------------------------------------------
// emb batch: emb_buf[sl][gru][n][512] (f16) = relu(xseg @ W_emb^T + b_emb)
// for steps [s0, s0+GBATCH). grid 512 = gru(2) x sl(16) x nchunk(16).
// ---------------------------------------------------------------------------
__global__ __launch_bounds__(256) void emb_kernel(
    const float* __restrict__ xs_seg, const float* __restrict__ xt_seg,
    const float* __restrict__ W_emb, const float* __restrict__ b_emb,
    _Float16* __restrict__ emb_buf, int s0) {
    int bid = blockIdx.x;
    int gru = bid >> 8, sl = (bid >> 4) & 15, nch = bid & 15;
    int step = s0 + sl, n0 = nch * 64;
    const float* xseg = gru ? xt_seg : xs_seg;
    __shared__ float xl[64 * 16];
    int tid = threadIdx.x;
    const float* src = xseg + ((size_t)step * N_ + n0) * SEG_;
    for (int i = tid; i < 1024; i += 256) xl[i] = src[i];
    float w1[16], w2[16];
#pragma unroll
    for (int q = 0; q < 16; ++q) {
        w1[q] = W_emb[tid * 16 + q];
        w2[q] = W_emb[(tid + 256) * 16 + q];
    }
    float b1 = b_emb[tid], b2 = b_emb[tid + 256];
    __syncthreads();
    _Float16* dst = emb_buf + ((size_t)(sl * 2 + gru) * N_ + n0) * D_;
    for (int r = 0; r < 64; ++r) {
        float a1 = b1, a2 = b2;
#pragma unroll
        for (int q = 0; q < 16; ++q) {
            float xv = xl[r * 16 + q];
            a1 = fmaf(xv, w1[q], a1);
            a2 = fmaf(xv, w2[q], a2);
        }
        a1 = a1 > 0.f ? a1 : 0.f;
        a2 = a2 > 0.f ? a2 : 0.f;
        dst[(size_t)r * D_ + tid]       = (_Float16)a1;
        dst[(size_t)r * D_ + tid + 256] = (_Float16)a2;
    }
}

// ---------------------------------------------------------------------------
// pack W~[gru][2048 rows][1024 k] f16. row = jg*64 + gate*16 + jl, j = jg*16+jl.
// k<512: emb-half (Wih); k>=512: h-half (Whh). gate 2 (in) zero in h-half,
// gate 3 (hn) zero in emb-half.
// ---------------------------------------------------------------------------
__global__ __launch_bounds__(256) void pack_w_kernel(
    const float* __restrict__ Wih_s, const float* __restrict__ Whh_s,
    const float* __restrict__ Wih_t, const float* __restrict__ Whh_t,
    _Float16* __restrict__ Wt) {
    int e = blockIdx.x * 256 + threadIdx.x;     // 2*2048*1024 total
    int k = e & 1023;
    int row = (e >> 10) & 2047;
    int gru = e >> 21;
    int gate = (row >> 4) & 3;
    int j = (row >> 6) * 16 + (row & 15);
    const float* Wih = gru ? Wih_t : Wih_s;
    const float* Whh = gru ? Whh_t : Whh_s;
    float v;
    if (k < 512) {
        v = (gate == 3) ? 0.f : Wih[(size_t)(gate * 512 + j) * 512 + k];
    } else {
        int g2 = (gate == 3) ? 2 : gate;
        v = (gate == 2) ? 0.f : Whh[(size_t)(g2 * 512 + j) * 512 + (k - 512)];
    }
    Wt[e] = (_Float16)v;
}

// pe[gru][n][512] f16: k<256 -> pos[k], else ch[c][k-256]
__global__ __launch_bounds__(256) void pack_pe_kernel(
    const float* __restrict__ pos_s, const float* __restrict__ ch_s,
    const float* __restrict__ pos_t, const float* __restrict__ ch_t,
    _Float16* __restrict__ pe) {
    int e = blockIdx.x * 256 + threadIdx.x;     // 2*1024*512 total
    int k = e & 511;
    int n = (e >> 9) & 1023;
    int gru = e >> 19;
    int c = n & 31;
    const float* pos = gru ? pos_t : pos_s;
    const float* ch  = gru ? ch_t  : ch_s;
    float v = (k < 256) ? pos[k] : ch[c * 256 + (k - 256)];
    pe[e] = (_Float16)v;
}

// ---------------------------------------------------------------------------
// One GRU step, both GRUs (blockIdx.z). MFMA f16 16x16x32.
// C[1024 x 2048] = A[1024 x 1024] * B;  A = [emb | h],
// B cols interleaved as j-groups of 16 x gates [r|z|in|hn] -> fused epilogue.
// Block: 64(M) x 128(N), 4 waves 2x2; wave = 32 rows x 64 cols (= 4 gates of
// one 16-j group) = 2x4 frags. XOR-swizzled LDS (slot = q ^ ((row>>1)&3))
// keeps ds_read_b128 at the free 2-way conflict level while staying
// compatible with global_load_lds's lane-contiguous placement.
// ---------------------------------------------------------------------------
__global__ __launch_bounds__(256, 2) void gru_mfma_kernel(
    const _Float16* __restrict__ a_lo,     // [gru][1024][512] emb or pe
    const _Float16* __restrict__ h_bf_in,  // [gru][1024][512]
    const _Float16* __restrict__ Wt,       // [gru][2048][1024]
    const float* __restrict__ bih_s, const float* __restrict__ bhh_s,
    const float* __restrict__ bih_t, const float* __restrict__ bhh_t,
    const float* __restrict__ hf_in,       // [gru][1024][512] fp32
    float* __restrict__ hf_out,
    _Float16* __restrict__ hbf_out) {
    __shared__ __align__(16) char sA[4096];
    __shared__ __align__(16) char sB[8192];
    int gru = blockIdx.z;
    int Mbase = blockIdx.y * 64;
    int Nt = blockIdx.x;                   // 0..15
    int tid = threadIdx.x;
    int w = tid >> 6, lane = tid & 63;
    int wm = w & 1, wn = w >> 1;

    // staging: this lane fetches chunk (row m, k-quad q=slot^((m>>1)&3))
    int sm = w * 16 + (lane >> 2);         // 0..63
    int sq = (lane & 3) ^ ((sm >> 1) & 3);
    const char* gAlo = (const char*)(a_lo    + (size_t)(gru * N_ + Mbase + sm) * D_) + 16 * sq;
    const char* gAhi = (const char*)(h_bf_in + (size_t)(gru * N_ + Mbase + sm) * D_) + 16 * sq;
    const char* gB0  = (const char*)(Wt + (size_t)gru * 2048 * 1024
                                        + (size_t)(Nt * 128 + sm) * 1024) + 16 * sq;
    const char* gB1  = gB0 + 64 * 2048;    // +64 rows (f(m) unchanged by +64)
    char* lA  = (char*)sA + w * 1024;      // wave-uniform LDS bases
    char* lB0 = (char*)sB + w * 1024;
    char* lB1 = (char*)sB + 4096 + w * 1024;

    // fragment read offsets
    int qq = lane >> 4, ml = lane & 15;
    int Ra0 = wm * 32 + ml, Ra1 = Ra0 + 16;
    int offA0 = Ra0 * 64 + 16 * (qq ^ ((Ra0 >> 1) & 3));
    int offA1 = Ra1 * 64 + 16 * (qq ^ ((Ra1 >> 1) & 3));
    int offB[4];
#pragma unroll
    for (int g = 0; g < 4; ++g) {
        int Rb = wn * 64 + g * 16 + ml;
        offB[g] = Rb * 64 + 16 * (qq ^ ((Rb >> 1) & 3));
    }

    f32x4 acc[2][4];
#pragma unroll
    for (int i = 0; i < 2; ++i)
#pragma unroll
        for (int g = 0; g < 4; ++g) {
            f32x4 z = {0.f, 0.f, 0.f, 0.f};
            acc[i][g] = z;
        }

    for (int kt = 0; kt < 32; ++kt) {
        __syncthreads();
        const char* srcA = (kt < 16) ? (gAlo + kt * 64) : (gAhi + (kt - 16) * 64);
        stage16(srcA, lA);
        stage16(gB0 + kt * 64, lB0);
        stage16(gB1 + kt * 64, lB1);
        asm volatile("s_waitcnt vmcnt(0)" ::: "memory");
        __syncthreads();
        f16x8 a0 = *(const f16x8*)(sA + offA0);
        f16x8 a1 = *(const f16x8*)(sA + offA1);
#pragma unroll
        for (int g = 0; g < 4; ++g) {
            f16x8 b = *(const f16x8*)(sB + offB[g]);
            acc[0][g] = __builtin_amdgcn_mfma_f32_16x16x32_f16(a0, b, acc[0][g], 0, 0, 0);
            acc[1][g] = __builtin_amdgcn_mfma_f32_16x16x32_f16(a1, b, acc[1][g], 0, 0, 0);
        }
    }

    // fused GRU epilogue: lane owns col j for all 4 gates in-register
    int j = (Nt * 2 + wn) * 16 + ml;
    const float* bi = gru ? bih_t : bih_s;
    const float* bh = gru ? bhh_t : bhh_s;
    float bir = bi[j], biz = bi[512 + j], bin = bi[1024 + j];
    float bhr = bh[j], bhz = bh[512 + j], bhn = bh[1024 + j];
#pragma unroll
    for (int rt = 0; rt < 2; ++rt) {
#pragma unroll
        for (int reg = 0; reg < 4; ++reg) {
            int row = Mbase + wm * 32 + rt * 16 + qq * 4 + reg;
            size_t idx = (size_t)(gru * N_ + row) * D_ + j;
            float Cr = acc[rt][0][reg], Cz = acc[rt][1][reg];
            float Ci = acc[rt][2][reg], Ch = acc[rt][3][reg];
            float r  = 1.f / (1.f + __expf(-(Cr + bir + bhr)));
            float z  = 1.f / (1.f + __expf(-(Cz + biz + bhz)));
            float nn = tanhf(Ci + bin + r * (Ch + bhn));
            float hp = hf_in[idx];
            float hnew = (1.f - z) * nn + z * hp;
            hf_out[idx]  = hnew;
            hbf_out[idx] = (_Float16)hnew;
        }
    }
}

// ---------------------------------------------------------------------------
__global__ __launch_bounds__(256) void head_kernel(
    const float* __restrict__ hs2, const float* __restrict__ ht2,
    const float* __restrict__ Wps, const float* __restrict__ bps,
    const float* __restrict__ Wpt, const float* __restrict__ bpt,
    const float* __restrict__ x, float* __restrict__ out) {
    int g = blockIdx.x * 256 + threadIdx.x;
    int n = g >> 4, p = g & 15;
    int b = n >> 5, c = n & 31;
    const float* hs = hs2 + (size_t)n * D_;
    const float* ht = ht2 + (size_t)n * D_;
    const float* ws = Wps + (size_t)p * D_;
    const float* wt = Wpt + (size_t)p * D_;
    float acc = bps[p] + bpt[p];
    for (int k = 0; k < D_; ++k) acc += hs[k] * ws[k] + ht[k] * wt[k];
    float last = x[((size_t)b * L_ + (L_ - 1)) * C_ + c];
    out[((size_t)b * SEG_ + p) * C_ + c] = acc + last;
}

// ---------------------------------------------------------------------------
extern "C" void kernel_launch(void* const* d_in, const int* in_sizes, int n_in,
                              void* d_out, int out_size, void* d_ws, size_t ws_size,
                              hipStream_t stream) {
    const float* x     = (const float*)d_in[0];
    const float* W_emb = (const float*)d_in[1];
    const float* b_emb = (const float*)d_in[2];
    const float* Wih_s = (const float*)d_in[3];
    const float* Whh_s = (const float*)d_in[4];
    const float* bih_s = (const float*)d_in[5];
    const float* bhh_s = (const float*)d_in[6];
    const float* Wih_t = (const float*)d_in[7];
    const float* Whh_t = (const float*)d_in[8];
    const float* bih_t = (const float*)d_in[9];
    const float* bhh_t = (const float*)d_in[10];
    const float* pos_s = (const float*)d_in[11];
    const float* ch_s  = (const float*)d_in[12];
    const float* pos_t = (const float*)d_in[13];
    const float* ch_t  = (const float*)d_in[14];
    const float* Wps   = (const float*)d_in[15];
    const float* bps   = (const float*)d_in[16];
    const float* Wpt   = (const float*)d_in[17];
    const float* bpt   = (const float*)d_in[18];
    float* out = (float*)d_out;

    char* p = (char*)d_ws;
    float* xs_seg = (float*)p;          p += (size_t)SX_ * N_ * SEG_ * 4;   // 4 MB
    float* xt_seg = (float*)p;          p += (size_t)SX_ * N_ * SEG_ * 4;   // 4 MB
    _Float16* emb_buf = (_Float16*)p;   p += (size_t)GBATCH * 2 * N_ * D_ * 2; // 32 MB
    _Float16* pe_buf  = (_Float16*)p;   p += (size_t)2 * N_ * D_ * 2;       // 2 MB
    _Float16* Wt      = (_Float16*)p;   p += (size_t)2 * 2048 * 1024 * 2;   // 8 MB
    float* hf0 = (float*)p;             p += (size_t)2 * N_ * D_ * 4;       // 4 MB
    float* hf1 = (float*)p;             p += (size_t)2 * N_ * D_ * 4;       // 4 MB
    _Float16* hbf0 = (_Float16*)p;      p += (size_t)2 * N_ * D_ * 2;       // 2 MB
    _Float16* hbf1 = (_Float16*)p;      p += (size_t)2 * N_ * D_ * 2;       // 2 MB

    hipMemsetAsync(hf0,  0, (size_t)2 * N_ * D_ * 4, stream);
    hipMemsetAsync(hbf0, 0, (size_t)2 * N_ * D_ * 2, stream);

    pack_w_kernel<<<(2 * 2048 * 1024) / 256, 256, 0, stream>>>(
        Wih_s, Whh_s, Wih_t, Whh_t, Wt);
    pack_pe_kernel<<<(2 * N_ * D_) / 256, 256, 0, stream>>>(
        pos_s, ch_s, pos_t, ch_t, pe_buf);
    prep_kernel<<<B_ * 4, 256, 0, stream>>>(x, xs_seg, xt_seg);

    dim3 grid(16, 16, 2);
    float* hf[2]     = {hf0, hf1};
    _Float16* hbf[2] = {hbf0, hbf1};
    for (int batch = 0; batch < SX_ / GBATCH; ++batch) {
        emb_kernel<<<2 * GBATCH * 16, 256, 0, stream>>>(
            xs_seg, xt_seg, W_emb, b_emb, emb_buf, batch * GBATCH);
        for (int sl = 0; sl < GBATCH; ++sl) {
            int s = batch * GBATCH + sl;
            int in = s & 1, o = 1 - in;
            gru_mfma_kernel<<<grid, 256, 0, stream>>>(
                emb_buf + (size_t)sl * 2 * N_ * D_, hbf[in], Wt,
                bih_s, bhh_s, bih_t, bhh_t, hf[in], hf[o], hbf[o]);
        }
    }
    // after step 63 state is in buffers 0; decoder step 0 -> 1
    gru_mfma_kernel<<<grid, 256, 0, stream>>>(
        pe_buf, hbf0, Wt, bih_s, bhh_s, bih_t, bhh_t, hf0, hf1, hbf1);

    head_kernel<<<N_ * SEG_ / 256, 256, 0, stream>>>(
        hf1, hf1 + (size_t)N_ * D_, Wps, bps, Wpt, bpt, x, out);
}